// Round 2
// baseline (568.599 us; speedup 1.0000x reference)
//
#include <hip/hip_runtime.h>
#include <cstdint>

// ---------------------------------------------------------------------------
// AnaphoricityScorer: scores = rough + FFNN([a, b, a*b, pw] @ W1 -> leaky -> W_out)
// Factorized: h = Ha[batch] + Hb[idx] + (a*b|pw)@W1cd + b1
//   Ha = mentions_batch @ W1[0:1024]       (1024x1024)
//   Hb = all_mentions  @ W1[1024:2048]     (8192x1024)
//   main GEMM: P[51200x1088] @ W1[2048:3136] with fused epilogue
// R2: main GEMM restructured for A-reuse — 1D grid 800 blocks, each block
//     loops 4 n-tiles (N=1024 split in 2 halves), XCD-chunked swizzle so the
//     two halves sharing an A-tile are L2/L3-adjacent. P built from bf16 srcs.
// ---------------------------------------------------------------------------

typedef short short8 __attribute__((ext_vector_type(8)));
typedef float f32x4 __attribute__((ext_vector_type(4)));

static __device__ __forceinline__ unsigned short f2bf(float x) {
  union { float f; unsigned u; } v; v.f = x;
  unsigned r = v.u + 0x7fffu + ((v.u >> 16) & 1u);  // RNE
  return (unsigned short)(r >> 16);
}
static __device__ __forceinline__ float bf2f(unsigned short u) {
  union { unsigned u; float f; } v; v.u = ((unsigned)u) << 16;
  return v.f;
}

static __device__ __forceinline__ void gload_lds16(const void* g, void* lds) {
  __builtin_amdgcn_global_load_lds(
      (const __attribute__((address_space(1))) void*)(unsigned long long)(uintptr_t)g,
      (__attribute__((address_space(3))) void*)(unsigned)(uintptr_t)lds, 16, 0, 0);
}

// W1 [3136][1024] f32 -> W1T [1024][3136] bf16 (tiled transpose)
__global__ void k_w1t(const float* __restrict__ W1, unsigned short* __restrict__ W1T) {
  __shared__ float t[64][65];
  int k0 = blockIdx.x * 64, n0 = blockIdx.y * 64;
  int c = threadIdx.x & 63, r4 = threadIdx.x >> 6;
#pragma unroll
  for (int rr = 0; rr < 16; ++rr) {
    int r = rr * 4 + r4;
    t[r][c] = W1[(size_t)(k0 + r) * 1024 + n0 + c];
  }
  __syncthreads();
#pragma unroll
  for (int rr = 0; rr < 16; ++rr) {
    int r = rr * 4 + r4;
    W1T[(size_t)(n0 + r) * 3136 + k0 + c] = f2bf(t[c][r]);
  }
}

// f32 -> bf16 elementwise, vectorized
__global__ void k_cvt(const float* __restrict__ s, unsigned short* __restrict__ d, int n4) {
  int i = blockIdx.x * 256 + threadIdx.x;
  if (i < n4) {
    float4 v = ((const float4*)s)[i];
    ushort4 o; o.x = f2bf(v.x); o.y = f2bf(v.y); o.z = f2bf(v.z); o.w = f2bf(v.w);
    ((ushort4*)d)[i] = o;
  }
}

// P[p] = [ bf16(a)*bf16(b) (1024) | bf16(pw) (64) ]  from bf16 sources
__global__ void k_pairs(const unsigned short* __restrict__ Abm,
                        const unsigned short* __restrict__ Aball,
                        const float* __restrict__ pw, const int* __restrict__ idx,
                        unsigned short* __restrict__ P) {
  int p = blockIdx.x, tid = threadIdx.x;
  int b = p / 50;
  int g = idx[p];
  ushort4 av = ((const ushort4*)(Abm + (size_t)b * 1024))[tid];
  ushort4 bv = ((const ushort4*)(Aball + (size_t)g * 1024))[tid];
  ushort4 o;
  o.x = f2bf(bf2f(av.x) * bf2f(bv.x));
  o.y = f2bf(bf2f(av.y) * bf2f(bv.y));
  o.z = f2bf(bf2f(av.z) * bf2f(bv.z));
  o.w = f2bf(bf2f(av.w) * bf2f(bv.w));
  ((ushort4*)(P + (size_t)p * 1088))[tid] = o;
  if (tid < 16) {
    float4 pv = ((const float4*)(pw + (size_t)p * 64))[tid];
    ushort4 q; q.x = f2bf(pv.x); q.y = f2bf(pv.y); q.z = f2bf(pv.z); q.w = f2bf(pv.w);
    ((ushort4*)(P + (size_t)p * 1088 + 1024))[tid] = q;
  }
}

// Plain GEMM (Ha, Hb): C[row][col] = sum_k A[row][k] * W1T[col][koff+k]
__global__ __launch_bounds__(256) void k_gemm0(
    const unsigned short* __restrict__ A, int ldaE, int K,
    const unsigned short* __restrict__ W1T, int koff, float* __restrict__ C) {
  __shared__ unsigned short As[128 * 64];
  __shared__ unsigned short Bs[128 * 64];
  int tid = threadIdx.x, lane = tid & 63, wave = tid >> 6;
  int row0 = blockIdx.x * 128, n0 = blockIdx.y * 128;
  int wr = wave >> 1, wc = wave & 1;
  int llo = lane & 15, lhi = lane >> 4;
  f32x4 acc[4][4] = {};
  const char* Ab = (const char*)A;
  const char* Bb = (const char*)W1T + (size_t)koff * 2;
  size_t ldaB = (size_t)ldaE * 2;
  int nkt = K >> 6;
  for (int kt = 0; kt < nkt; ++kt) {
#pragma unroll
    for (int c = 0; c < 4; ++c) {
      int o = c * 4096 + wave * 1024 + lane * 16;
      int r = o >> 7, kb = o & 127;
      gload_lds16(Ab + (size_t)(row0 + r) * ldaB + (size_t)kt * 128 + kb,
                  (char*)As + c * 4096 + wave * 1024);
      gload_lds16(Bb + (size_t)(n0 + r) * 6272 + (size_t)kt * 128 + kb,
                  (char*)Bs + c * 4096 + wave * 1024);
    }
    __syncthreads();
#pragma unroll
    for (int ks = 0; ks < 2; ++ks) {
      short8 af[4], bfr[4];
#pragma unroll
      for (int m = 0; m < 4; ++m)
        af[m] = *(const short8*)(As + (wr * 64 + m * 16 + llo) * 64 + ks * 32 + lhi * 8);
#pragma unroll
      for (int n = 0; n < 4; ++n)
        bfr[n] = *(const short8*)(Bs + (wc * 64 + n * 16 + llo) * 64 + ks * 32 + lhi * 8);
#pragma unroll
      for (int m = 0; m < 4; ++m)
#pragma unroll
        for (int n = 0; n < 4; ++n)
          acc[m][n] = __builtin_amdgcn_mfma_f32_16x16x32_bf16(af[m], bfr[n], acc[m][n], 0, 0, 0);
    }
    __syncthreads();
  }
#pragma unroll
  for (int m = 0; m < 4; ++m)
#pragma unroll
    for (int i = 0; i < 4; ++i) {
      int tr = wr * 64 + m * 16 + lhi * 4 + i;
#pragma unroll
      for (int n = 0; n < 4; ++n) {
        int tc = wc * 64 + n * 16 + llo;
        C[(size_t)(row0 + tr) * 1024 + n0 + tc] = acc[m][n][i];
      }
    }
}

// Main GEMM with A-reuse: each block owns 128 rows, loops 4 n-tiles (one half
// of N=1024), fused epilogue -> partial[p][16].
__global__ __launch_bounds__(256) void k_main(
    const unsigned short* __restrict__ P, const unsigned short* __restrict__ W1T,
    float* __restrict__ partial,
    const float* __restrict__ Ha, const float* __restrict__ Hb,
    const float* __restrict__ b1, const float* __restrict__ Wout,
    const int* __restrict__ idx) {
  __shared__ unsigned short As[128 * 64];
  __shared__ unsigned short Bs[128 * 64];
  int tid = threadIdx.x, lane = tid & 63, wave = tid >> 6;
  // bijective XCD-chunked swizzle: 800 blocks, 8 XCDs, 100/chunk.
  int bid = blockIdx.x;
  int orig = (bid & 7) * 100 + (bid >> 3);
  int xr = orig >> 1, yh = orig & 1;  // (x, half) pairs adjacent -> same XCD
  int row0 = xr * 128;
  int wr = wave >> 1, wc = wave & 1;
  int llo = lane & 15, lhi = lane >> 4;
  const char* Ab = (const char*)P;
  const char* Bb = (const char*)W1T + 2048 * 2;  // koff = 2048
  for (int nt = 0; nt < 4; ++nt) {
    int n0 = (yh * 4 + nt) * 128;
    f32x4 acc[4][4] = {};
    for (int kt = 0; kt < 17; ++kt) {
#pragma unroll
      for (int c = 0; c < 4; ++c) {
        int o = c * 4096 + wave * 1024 + lane * 16;
        int r = o >> 7, kb = o & 127;
        gload_lds16(Ab + (size_t)(row0 + r) * 2176 + (size_t)kt * 128 + kb,
                    (char*)As + c * 4096 + wave * 1024);
        gload_lds16(Bb + (size_t)(n0 + r) * 6272 + (size_t)kt * 128 + kb,
                    (char*)Bs + c * 4096 + wave * 1024);
      }
      __syncthreads();
#pragma unroll
      for (int ks = 0; ks < 2; ++ks) {
        short8 af[4], bfr[4];
#pragma unroll
        for (int m = 0; m < 4; ++m)
          af[m] = *(const short8*)(As + (wr * 64 + m * 16 + llo) * 64 + ks * 32 + lhi * 8);
#pragma unroll
        for (int n = 0; n < 4; ++n)
          bfr[n] = *(const short8*)(Bs + (wc * 64 + n * 16 + llo) * 64 + ks * 32 + lhi * 8);
#pragma unroll
        for (int m = 0; m < 4; ++m)
#pragma unroll
          for (int n = 0; n < 4; ++n)
            acc[m][n] = __builtin_amdgcn_mfma_f32_16x16x32_bf16(af[m], bfr[n], acc[m][n], 0, 0, 0);
      }
      __syncthreads();
    }
    // fused epilogue for this n-tile
    float b1v[4], wov[4];
    int coln[4];
#pragma unroll
    for (int n = 0; n < 4; ++n) {
      coln[n] = n0 + wc * 64 + n * 16 + llo;
      b1v[n] = b1[coln[n]];
      wov[n] = Wout[coln[n]];
    }
    int chunk = (yh * 4 + nt) * 2 + wc;
#pragma unroll
    for (int m = 0; m < 4; ++m)
#pragma unroll
      for (int i = 0; i < 4; ++i) {
        int p = row0 + wr * 64 + m * 16 + lhi * 4 + i;
        int bb = p / 50;
        int gg = idx[p];
        const float* Har = Ha + (size_t)bb * 1024;
        const float* Hbr = Hb + (size_t)gg * 1024;
        float s = 0.f;
#pragma unroll
        for (int n = 0; n < 4; ++n) {
          float h = acc[m][n][i] + Har[coln[n]] + Hbr[coln[n]] + b1v[n];
          h = h > 0.f ? h : 0.01f * h;
          s += h * wov[n];
        }
        s += __shfl_xor(s, 1, 64);
        s += __shfl_xor(s, 2, 64);
        s += __shfl_xor(s, 4, 64);
        s += __shfl_xor(s, 8, 64);
        if (llo == 0) partial[(size_t)p * 16 + chunk] = s;
      }
  }
}

__global__ void k_final(const float* __restrict__ partial, const float* __restrict__ rough,
                        const float* __restrict__ bout, float* __restrict__ out) {
  int t = blockIdx.x * 256 + threadIdx.x;
  if (t < 51200) {
    float s = rough[t] + bout[0];
    const float* pp = partial + (size_t)t * 16;
#pragma unroll
    for (int c = 0; c < 16; ++c) s += pp[c];
    out[(size_t)(t / 50) * 51 + 1 + (t % 50)] = s;
  }
  if (t < 1024) out[(size_t)t * 51] = 1e-7f;
}

extern "C" void kernel_launch(void* const* d_in, const int* in_sizes, int n_in,
                              void* d_out, int out_size, void* d_ws, size_t ws_size,
                              hipStream_t stream) {
  (void)in_sizes; (void)n_in; (void)out_size;
  const float* allm  = (const float*)d_in[0];  // [8192][1024]
  const float* am    = (const float*)d_in[1];  // [1024][1024]
  const float* pw    = (const float*)d_in[2];  // [1024][50][64]
  const float* rough = (const float*)d_in[3];  // [1024][50]
  const float* W1    = (const float*)d_in[4];  // [3136][1024]
  const float* b1    = (const float*)d_in[5];  // [1024]
  const float* Wout  = (const float*)d_in[6];  // [1024]
  const float* bout  = (const float*)d_in[7];  // [1]
  const int*   idx   = (const int*)d_in[8];    // [1024][50]
  float* out = (float*)d_out;                  // [1024][51]

  char* w = (char*)d_ws;
  unsigned short* W1T   = (unsigned short*)w; w += (size_t)1024 * 3136 * 2;
  unsigned short* Abm   = (unsigned short*)w; w += (size_t)1024 * 1024 * 2;
  unsigned short* Aball = (unsigned short*)w; w += (size_t)8192 * 1024 * 2;
  unsigned short* P     = (unsigned short*)w; w += (size_t)51200 * 1088 * 2;
  float* Ha             = (float*)w;          w += (size_t)1024 * 1024 * 4;
  float* Hb             = (float*)w;          w += (size_t)8192 * 1024 * 4;
  float* part           = (float*)w;          w += (size_t)51200 * 16 * 4;
  size_t need = (size_t)(w - (char*)d_ws);
  if (ws_size < need) return;

  k_w1t<<<dim3(49, 16), 256, 0, stream>>>(W1, W1T);
  k_cvt<<<dim3(1024), 256, 0, stream>>>(am, Abm, 1024 * 1024 / 4);
  k_cvt<<<dim3(8192), 256, 0, stream>>>(allm, Aball, 8192 * 1024 / 4);
  k_pairs<<<dim3(51200), 256, 0, stream>>>(Abm, Aball, pw, idx, P);
  k_gemm0<<<dim3(8, 8), 256, 0, stream>>>(Abm, 1024, 1024, W1T, 0, Ha);
  k_gemm0<<<dim3(64, 8), 256, 0, stream>>>(Aball, 1024, 1024, W1T, 1024, Hb);
  k_main<<<dim3(800), 256, 0, stream>>>(P, W1T, part, Ha, Hb, b1, Wout, idx);
  k_final<<<dim3(200), 256, 0, stream>>>(part, rough, bout, out);
}

// Round 3
// 358.994 us; speedup vs baseline: 1.5839x; 1.5839x over previous
//
#include <hip/hip_runtime.h>
#include <cstdint>

// ---------------------------------------------------------------------------
// AnaphoricityScorer: scores = rough + FFNN([a, b, a*b, pw] @ W1 -> leaky -> W_out)
// Factorized: h = Ha[batch] + Hb[idx] + (a*b|pw)@W1cd + b1
//   Ha = mentions_batch @ W1[0:1024]       (1024x1024)
//   Hb = all_mentions  @ W1[1024:2048]     (8192x1024)
//   main GEMM: P[51200x1088] @ W1[2048:3136] with fused epilogue
// R3: back to R1's one-tile-per-block k_main (88 VGPR, high issue rate), with
//     a bijective XCD-chunked swizzle: XCD k owns x in [50k,50k+50), y fastest,
//     so the 8 blocks sharing an A-tile co-reside on one XCD's L2.
// ---------------------------------------------------------------------------

typedef short short8 __attribute__((ext_vector_type(8)));
typedef float f32x4 __attribute__((ext_vector_type(4)));

static __device__ __forceinline__ unsigned short f2bf(float x) {
  union { float f; unsigned u; } v; v.f = x;
  unsigned r = v.u + 0x7fffu + ((v.u >> 16) & 1u);  // RNE
  return (unsigned short)(r >> 16);
}
static __device__ __forceinline__ float bf2f(unsigned short u) {
  union { unsigned u; float f; } v; v.u = ((unsigned)u) << 16;
  return v.f;
}

static __device__ __forceinline__ void gload_lds16(const void* g, void* lds) {
  __builtin_amdgcn_global_load_lds(
      (const __attribute__((address_space(1))) void*)(unsigned long long)(uintptr_t)g,
      (__attribute__((address_space(3))) void*)(unsigned)(uintptr_t)lds, 16, 0, 0);
}

// W1 [3136][1024] f32 -> W1T [1024][3136] bf16 (tiled transpose)
__global__ void k_w1t(const float* __restrict__ W1, unsigned short* __restrict__ W1T) {
  __shared__ float t[64][65];
  int k0 = blockIdx.x * 64, n0 = blockIdx.y * 64;
  int c = threadIdx.x & 63, r4 = threadIdx.x >> 6;
#pragma unroll
  for (int rr = 0; rr < 16; ++rr) {
    int r = rr * 4 + r4;
    t[r][c] = W1[(size_t)(k0 + r) * 1024 + n0 + c];
  }
  __syncthreads();
#pragma unroll
  for (int rr = 0; rr < 16; ++rr) {
    int r = rr * 4 + r4;
    W1T[(size_t)(n0 + r) * 3136 + k0 + c] = f2bf(t[c][r]);
  }
}

// f32 -> bf16 elementwise, vectorized
__global__ void k_cvt(const float* __restrict__ s, unsigned short* __restrict__ d, int n4) {
  int i = blockIdx.x * 256 + threadIdx.x;
  if (i < n4) {
    float4 v = ((const float4*)s)[i];
    ushort4 o; o.x = f2bf(v.x); o.y = f2bf(v.y); o.z = f2bf(v.z); o.w = f2bf(v.w);
    ((ushort4*)d)[i] = o;
  }
}

// P[p] = [ bf16(a)*bf16(b) (1024) | bf16(pw) (64) ]  from bf16 sources
__global__ void k_pairs(const unsigned short* __restrict__ Abm,
                        const unsigned short* __restrict__ Aball,
                        const float* __restrict__ pw, const int* __restrict__ idx,
                        unsigned short* __restrict__ P) {
  int p = blockIdx.x, tid = threadIdx.x;
  int b = p / 50;
  int g = idx[p];
  ushort4 av = ((const ushort4*)(Abm + (size_t)b * 1024))[tid];
  ushort4 bv = ((const ushort4*)(Aball + (size_t)g * 1024))[tid];
  ushort4 o;
  o.x = f2bf(bf2f(av.x) * bf2f(bv.x));
  o.y = f2bf(bf2f(av.y) * bf2f(bv.y));
  o.z = f2bf(bf2f(av.z) * bf2f(bv.z));
  o.w = f2bf(bf2f(av.w) * bf2f(bv.w));
  ((ushort4*)(P + (size_t)p * 1088))[tid] = o;
  if (tid < 16) {
    float4 pv = ((const float4*)(pw + (size_t)p * 64))[tid];
    ushort4 q; q.x = f2bf(pv.x); q.y = f2bf(pv.y); q.z = f2bf(pv.z); q.w = f2bf(pv.w);
    ((ushort4*)(P + (size_t)p * 1088 + 1024))[tid] = q;
  }
}

// Plain GEMM (Ha, Hb): C[row][col] = sum_k A[row][k] * W1T[col][koff+k]
__global__ __launch_bounds__(256) void k_gemm0(
    const unsigned short* __restrict__ A, int ldaE, int K,
    const unsigned short* __restrict__ W1T, int koff, float* __restrict__ C) {
  __shared__ unsigned short As[128 * 64];
  __shared__ unsigned short Bs[128 * 64];
  int tid = threadIdx.x, lane = tid & 63, wave = tid >> 6;
  int row0 = blockIdx.x * 128, n0 = blockIdx.y * 128;
  int wr = wave >> 1, wc = wave & 1;
  int llo = lane & 15, lhi = lane >> 4;
  f32x4 acc[4][4] = {};
  const char* Ab = (const char*)A;
  const char* Bb = (const char*)W1T + (size_t)koff * 2;
  size_t ldaB = (size_t)ldaE * 2;
  int nkt = K >> 6;
  for (int kt = 0; kt < nkt; ++kt) {
#pragma unroll
    for (int c = 0; c < 4; ++c) {
      int o = c * 4096 + wave * 1024 + lane * 16;
      int r = o >> 7, kb = o & 127;
      gload_lds16(Ab + (size_t)(row0 + r) * ldaB + (size_t)kt * 128 + kb,
                  (char*)As + c * 4096 + wave * 1024);
      gload_lds16(Bb + (size_t)(n0 + r) * 6272 + (size_t)kt * 128 + kb,
                  (char*)Bs + c * 4096 + wave * 1024);
    }
    __syncthreads();
#pragma unroll
    for (int ks = 0; ks < 2; ++ks) {
      short8 af[4], bfr[4];
#pragma unroll
      for (int m = 0; m < 4; ++m)
        af[m] = *(const short8*)(As + (wr * 64 + m * 16 + llo) * 64 + ks * 32 + lhi * 8);
#pragma unroll
      for (int n = 0; n < 4; ++n)
        bfr[n] = *(const short8*)(Bs + (wc * 64 + n * 16 + llo) * 64 + ks * 32 + lhi * 8);
#pragma unroll
      for (int m = 0; m < 4; ++m)
#pragma unroll
        for (int n = 0; n < 4; ++n)
          acc[m][n] = __builtin_amdgcn_mfma_f32_16x16x32_bf16(af[m], bfr[n], acc[m][n], 0, 0, 0);
    }
    __syncthreads();
  }
#pragma unroll
  for (int m = 0; m < 4; ++m)
#pragma unroll
    for (int i = 0; i < 4; ++i) {
      int tr = wr * 64 + m * 16 + lhi * 4 + i;
#pragma unroll
      for (int n = 0; n < 4; ++n) {
        int tc = wc * 64 + n * 16 + llo;
        C[(size_t)(row0 + tr) * 1024 + n0 + tc] = acc[m][n][i];
      }
    }
}

// Main GEMM: one 128x128 tile per block (R1 structure), XCD-chunked swizzle.
// 3200 blocks: xcd = id%8 owns x in [50*xcd, 50*xcd+50), y fastest.
__global__ __launch_bounds__(256) void k_main(
    const unsigned short* __restrict__ P, const unsigned short* __restrict__ W1T,
    float* __restrict__ partial,
    const float* __restrict__ Ha, const float* __restrict__ Hb,
    const float* __restrict__ b1, const float* __restrict__ Wout,
    const int* __restrict__ idx) {
  __shared__ unsigned short As[128 * 64];
  __shared__ unsigned short Bs[128 * 64];
  int tid = threadIdx.x, lane = tid & 63, wave = tid >> 6;
  int id = blockIdx.x;
  int r = id >> 3;
  int x = (id & 7) * 50 + (r >> 3);
  int y = r & 7;
  int row0 = x * 128, n0 = y * 128;
  int wr = wave >> 1, wc = wave & 1;
  int llo = lane & 15, lhi = lane >> 4;
  f32x4 acc[4][4] = {};
  const char* Ab = (const char*)P;
  const char* Bb = (const char*)W1T + 2048 * 2;  // koff = 2048
  for (int kt = 0; kt < 17; ++kt) {
#pragma unroll
    for (int c = 0; c < 4; ++c) {
      int o = c * 4096 + wave * 1024 + lane * 16;
      int rr = o >> 7, kb = o & 127;
      gload_lds16(Ab + (size_t)(row0 + rr) * 2176 + (size_t)kt * 128 + kb,
                  (char*)As + c * 4096 + wave * 1024);
      gload_lds16(Bb + (size_t)(n0 + rr) * 6272 + (size_t)kt * 128 + kb,
                  (char*)Bs + c * 4096 + wave * 1024);
    }
    __syncthreads();
#pragma unroll
    for (int ks = 0; ks < 2; ++ks) {
      short8 af[4], bfr[4];
#pragma unroll
      for (int m = 0; m < 4; ++m)
        af[m] = *(const short8*)(As + (wr * 64 + m * 16 + llo) * 64 + ks * 32 + lhi * 8);
#pragma unroll
      for (int n = 0; n < 4; ++n)
        bfr[n] = *(const short8*)(Bs + (wc * 64 + n * 16 + llo) * 64 + ks * 32 + lhi * 8);
#pragma unroll
      for (int m = 0; m < 4; ++m)
#pragma unroll
        for (int n = 0; n < 4; ++n)
          acc[m][n] = __builtin_amdgcn_mfma_f32_16x16x32_bf16(af[m], bfr[n], acc[m][n], 0, 0, 0);
    }
    __syncthreads();
  }
  // fused epilogue -> partial[p][16]
  float b1v[4], wov[4];
  int coln[4];
#pragma unroll
  for (int n = 0; n < 4; ++n) {
    coln[n] = n0 + wc * 64 + n * 16 + llo;
    b1v[n] = b1[coln[n]];
    wov[n] = Wout[coln[n]];
  }
  int chunk = y * 2 + wc;
#pragma unroll
  for (int m = 0; m < 4; ++m)
#pragma unroll
    for (int i = 0; i < 4; ++i) {
      int p = row0 + wr * 64 + m * 16 + lhi * 4 + i;
      int bb = p / 50;
      int gg = idx[p];
      const float* Har = Ha + (size_t)bb * 1024;
      const float* Hbr = Hb + (size_t)gg * 1024;
      float s = 0.f;
#pragma unroll
      for (int n = 0; n < 4; ++n) {
        float h = acc[m][n][i] + Har[coln[n]] + Hbr[coln[n]] + b1v[n];
        h = h > 0.f ? h : 0.01f * h;
        s += h * wov[n];
      }
      s += __shfl_xor(s, 1, 64);
      s += __shfl_xor(s, 2, 64);
      s += __shfl_xor(s, 4, 64);
      s += __shfl_xor(s, 8, 64);
      if (llo == 0) partial[(size_t)p * 16 + chunk] = s;
    }
}

__global__ void k_final(const float* __restrict__ partial, const float* __restrict__ rough,
                        const float* __restrict__ bout, float* __restrict__ out) {
  int t = blockIdx.x * 256 + threadIdx.x;
  if (t < 51200) {
    float s = rough[t] + bout[0];
    const float* pp = partial + (size_t)t * 16;
#pragma unroll
    for (int c = 0; c < 16; ++c) s += pp[c];
    out[(size_t)(t / 50) * 51 + 1 + (t % 50)] = s;
  }
  if (t < 1024) out[(size_t)t * 51] = 1e-7f;
}

extern "C" void kernel_launch(void* const* d_in, const int* in_sizes, int n_in,
                              void* d_out, int out_size, void* d_ws, size_t ws_size,
                              hipStream_t stream) {
  (void)in_sizes; (void)n_in; (void)out_size;
  const float* allm  = (const float*)d_in[0];  // [8192][1024]
  const float* am    = (const float*)d_in[1];  // [1024][1024]
  const float* pw    = (const float*)d_in[2];  // [1024][50][64]
  const float* rough = (const float*)d_in[3];  // [1024][50]
  const float* W1    = (const float*)d_in[4];  // [3136][1024]
  const float* b1    = (const float*)d_in[5];  // [1024]
  const float* Wout  = (const float*)d_in[6];  // [1024]
  const float* bout  = (const float*)d_in[7];  // [1]
  const int*   idx   = (const int*)d_in[8];    // [1024][50]
  float* out = (float*)d_out;                  // [1024][51]

  char* w = (char*)d_ws;
  unsigned short* W1T   = (unsigned short*)w; w += (size_t)1024 * 3136 * 2;
  unsigned short* Abm   = (unsigned short*)w; w += (size_t)1024 * 1024 * 2;
  unsigned short* Aball = (unsigned short*)w; w += (size_t)8192 * 1024 * 2;
  unsigned short* P     = (unsigned short*)w; w += (size_t)51200 * 1088 * 2;
  float* Ha             = (float*)w;          w += (size_t)1024 * 1024 * 4;
  float* Hb             = (float*)w;          w += (size_t)8192 * 1024 * 4;
  float* part           = (float*)w;          w += (size_t)51200 * 16 * 4;
  size_t need = (size_t)(w - (char*)d_ws);
  if (ws_size < need) return;

  k_w1t<<<dim3(49, 16), 256, 0, stream>>>(W1, W1T);
  k_cvt<<<dim3(1024), 256, 0, stream>>>(am, Abm, 1024 * 1024 / 4);
  k_cvt<<<dim3(8192), 256, 0, stream>>>(allm, Aball, 8192 * 1024 / 4);
  k_pairs<<<dim3(51200), 256, 0, stream>>>(Abm, Aball, pw, idx, P);
  k_gemm0<<<dim3(8, 8), 256, 0, stream>>>(Abm, 1024, 1024, W1T, 0, Ha);
  k_gemm0<<<dim3(64, 8), 256, 0, stream>>>(Aball, 1024, 1024, W1T, 1024, Hb);
  k_main<<<dim3(3200), 256, 0, stream>>>(P, W1T, part, Ha, Hb, b1, Wout, idx);
  k_final<<<dim3(200), 256, 0, stream>>>(part, rough, bout, out);
}

// Round 4
// 309.429 us; speedup vs baseline: 1.8376x; 1.1602x over previous
//
#include <hip/hip_runtime.h>
#include <cstdint>

// ---------------------------------------------------------------------------
// AnaphoricityScorer: scores = rough + FFNN([a, b, a*b, pw] @ W1 -> leaky -> W_out)
// Factorized: h = Ha[batch] + Hb[idx] + (a*b|pw)@W1cd + b1
// R4: T3 "minimum 2-phase" pipeline on both GEMMs — double-buffered LDS,
//     STAGE(next) issued BEFORE compute(cur), ONE barrier per K-step.
//     Removes the exposed load latency of the 2-barrier structure (R3 showed
//     fetch halved but time flat => latency-bound, not BW-bound).
// ---------------------------------------------------------------------------

typedef short short8 __attribute__((ext_vector_type(8)));
typedef float f32x4 __attribute__((ext_vector_type(4)));

static __device__ __forceinline__ unsigned short f2bf(float x) {
  union { float f; unsigned u; } v; v.f = x;
  unsigned r = v.u + 0x7fffu + ((v.u >> 16) & 1u);  // RNE
  return (unsigned short)(r >> 16);
}
static __device__ __forceinline__ float bf2f(unsigned short u) {
  union { unsigned u; float f; } v; v.u = ((unsigned)u) << 16;
  return v.f;
}

static __device__ __forceinline__ void gload_lds16(const void* g, void* lds) {
  __builtin_amdgcn_global_load_lds(
      (const __attribute__((address_space(1))) void*)(unsigned long long)(uintptr_t)g,
      (__attribute__((address_space(3))) void*)(unsigned)(uintptr_t)lds, 16, 0, 0);
}

// W1 [3136][1024] f32 -> W1T [1024][3136] bf16 (tiled transpose)
__global__ void k_w1t(const float* __restrict__ W1, unsigned short* __restrict__ W1T) {
  __shared__ float t[64][65];
  int k0 = blockIdx.x * 64, n0 = blockIdx.y * 64;
  int c = threadIdx.x & 63, r4 = threadIdx.x >> 6;
#pragma unroll
  for (int rr = 0; rr < 16; ++rr) {
    int r = rr * 4 + r4;
    t[r][c] = W1[(size_t)(k0 + r) * 1024 + n0 + c];
  }
  __syncthreads();
#pragma unroll
  for (int rr = 0; rr < 16; ++rr) {
    int r = rr * 4 + r4;
    W1T[(size_t)(n0 + r) * 3136 + k0 + c] = f2bf(t[c][r]);
  }
}

// f32 -> bf16 elementwise, vectorized
__global__ void k_cvt(const float* __restrict__ s, unsigned short* __restrict__ d, int n4) {
  int i = blockIdx.x * 256 + threadIdx.x;
  if (i < n4) {
    float4 v = ((const float4*)s)[i];
    ushort4 o; o.x = f2bf(v.x); o.y = f2bf(v.y); o.z = f2bf(v.z); o.w = f2bf(v.w);
    ((ushort4*)d)[i] = o;
  }
}

// P[p] = [ bf16(a)*bf16(b) (1024) | bf16(pw) (64) ]  from bf16 sources
__global__ void k_pairs(const unsigned short* __restrict__ Abm,
                        const unsigned short* __restrict__ Aball,
                        const float* __restrict__ pw, const int* __restrict__ idx,
                        unsigned short* __restrict__ P) {
  int p = blockIdx.x, tid = threadIdx.x;
  int b = p / 50;
  int g = idx[p];
  ushort4 av = ((const ushort4*)(Abm + (size_t)b * 1024))[tid];
  ushort4 bv = ((const ushort4*)(Aball + (size_t)g * 1024))[tid];
  ushort4 o;
  o.x = f2bf(bf2f(av.x) * bf2f(bv.x));
  o.y = f2bf(bf2f(av.y) * bf2f(bv.y));
  o.z = f2bf(bf2f(av.z) * bf2f(bv.z));
  o.w = f2bf(bf2f(av.w) * bf2f(bv.w));
  ((ushort4*)(P + (size_t)p * 1088))[tid] = o;
  if (tid < 16) {
    float4 pv = ((const float4*)(pw + (size_t)p * 64))[tid];
    ushort4 q; q.x = f2bf(pv.x); q.y = f2bf(pv.y); q.z = f2bf(pv.z); q.w = f2bf(pv.w);
    ((ushort4*)(P + (size_t)p * 1088 + 1024))[tid] = q;
  }
}

// Plain GEMM (Ha, Hb), 2-phase double-buffered.
__global__ __launch_bounds__(256) void k_gemm0(
    const unsigned short* __restrict__ A, int ldaE, int K,
    const unsigned short* __restrict__ W1T, int koff, float* __restrict__ C) {
  __shared__ unsigned short As[2][128 * 64];
  __shared__ unsigned short Bs[2][128 * 64];
  int tid = threadIdx.x, lane = tid & 63, wave = tid >> 6;
  int row0 = blockIdx.x * 128, n0 = blockIdx.y * 128;
  int wr = wave >> 1, wc = wave & 1;
  int llo = lane & 15, lhi = lane >> 4;
  f32x4 acc[4][4] = {};
  const char* Ab = (const char*)A;
  const char* Bb = (const char*)W1T + (size_t)koff * 2;
  size_t ldaB = (size_t)ldaE * 2;
  int nkt = K >> 6;
  int o = wave * 1024 + lane * 16;

  auto stage = [&](int buf, int kt) {
#pragma unroll
    for (int c = 0; c < 4; ++c) {
      int oo = c * 4096 + o;
      int rr = oo >> 7, kb = oo & 127;
      gload_lds16(Ab + (size_t)(row0 + rr) * ldaB + (size_t)kt * 128 + kb,
                  (char*)As + buf * 16384 + oo);
      gload_lds16(Bb + (size_t)(n0 + rr) * 6272 + (size_t)kt * 128 + kb,
                  (char*)Bs + buf * 16384 + oo);
    }
  };

  stage(0, 0);
  __syncthreads();
  int cur = 0;
  for (int kt = 0; kt < nkt; ++kt) {
    if (kt + 1 < nkt) stage(cur ^ 1, kt + 1);
    const unsigned short* as = As[cur];
    const unsigned short* bs = Bs[cur];
#pragma unroll
    for (int ks = 0; ks < 2; ++ks) {
      short8 af[4], bfr[4];
#pragma unroll
      for (int m = 0; m < 4; ++m)
        af[m] = *(const short8*)(as + (wr * 64 + m * 16 + llo) * 64 + ks * 32 + lhi * 8);
#pragma unroll
      for (int n = 0; n < 4; ++n)
        bfr[n] = *(const short8*)(bs + (wc * 64 + n * 16 + llo) * 64 + ks * 32 + lhi * 8);
#pragma unroll
      for (int m = 0; m < 4; ++m)
#pragma unroll
        for (int n = 0; n < 4; ++n)
          acc[m][n] = __builtin_amdgcn_mfma_f32_16x16x32_bf16(af[m], bfr[n], acc[m][n], 0, 0, 0);
    }
    __syncthreads();
    cur ^= 1;
  }
#pragma unroll
  for (int m = 0; m < 4; ++m)
#pragma unroll
    for (int i = 0; i < 4; ++i) {
      int tr = wr * 64 + m * 16 + lhi * 4 + i;
#pragma unroll
      for (int n = 0; n < 4; ++n) {
        int tc = wc * 64 + n * 16 + llo;
        C[(size_t)(row0 + tr) * 1024 + n0 + tc] = acc[m][n][i];
      }
    }
}

// Main GEMM: one 128x128 tile per block, XCD-chunked swizzle, 2-phase pipeline,
// fused epilogue -> partial[p][16].
__global__ __launch_bounds__(256) void k_main(
    const unsigned short* __restrict__ P, const unsigned short* __restrict__ W1T,
    float* __restrict__ partial,
    const float* __restrict__ Ha, const float* __restrict__ Hb,
    const float* __restrict__ b1, const float* __restrict__ Wout,
    const int* __restrict__ idx) {
  __shared__ unsigned short As[2][128 * 64];
  __shared__ unsigned short Bs[2][128 * 64];
  int tid = threadIdx.x, lane = tid & 63, wave = tid >> 6;
  int id = blockIdx.x;
  int r = id >> 3;
  int x = (id & 7) * 50 + (r >> 3);
  int y = r & 7;
  int row0 = x * 128, n0 = y * 128;
  int wr = wave >> 1, wc = wave & 1;
  int llo = lane & 15, lhi = lane >> 4;
  f32x4 acc[4][4] = {};
  const char* Ab = (const char*)P;
  const char* Bb = (const char*)W1T + 2048 * 2;  // koff = 2048
  int o = wave * 1024 + lane * 16;

  auto stage = [&](int buf, int kt) {
#pragma unroll
    for (int c = 0; c < 4; ++c) {
      int oo = c * 4096 + o;
      int rr = oo >> 7, kb = oo & 127;
      gload_lds16(Ab + (size_t)(row0 + rr) * 2176 + (size_t)kt * 128 + kb,
                  (char*)As + buf * 16384 + oo);
      gload_lds16(Bb + (size_t)(n0 + rr) * 6272 + (size_t)kt * 128 + kb,
                  (char*)Bs + buf * 16384 + oo);
    }
  };

  stage(0, 0);
  __syncthreads();
  int cur = 0;
  for (int kt = 0; kt < 17; ++kt) {
    if (kt + 1 < 17) stage(cur ^ 1, kt + 1);
    const unsigned short* as = As[cur];
    const unsigned short* bs = Bs[cur];
#pragma unroll
    for (int ks = 0; ks < 2; ++ks) {
      short8 af[4], bfr[4];
#pragma unroll
      for (int m = 0; m < 4; ++m)
        af[m] = *(const short8*)(as + (wr * 64 + m * 16 + llo) * 64 + ks * 32 + lhi * 8);
#pragma unroll
      for (int n = 0; n < 4; ++n)
        bfr[n] = *(const short8*)(bs + (wc * 64 + n * 16 + llo) * 64 + ks * 32 + lhi * 8);
#pragma unroll
      for (int m = 0; m < 4; ++m)
#pragma unroll
        for (int n = 0; n < 4; ++n)
          acc[m][n] = __builtin_amdgcn_mfma_f32_16x16x32_bf16(af[m], bfr[n], acc[m][n], 0, 0, 0);
    }
    __syncthreads();
    cur ^= 1;
  }
  // fused epilogue -> partial[p][16]
  float b1v[4], wov[4];
  int coln[4];
#pragma unroll
  for (int n = 0; n < 4; ++n) {
    coln[n] = n0 + wc * 64 + n * 16 + llo;
    b1v[n] = b1[coln[n]];
    wov[n] = Wout[coln[n]];
  }
  int chunk = y * 2 + wc;
#pragma unroll
  for (int m = 0; m < 4; ++m)
#pragma unroll
    for (int i = 0; i < 4; ++i) {
      int p = row0 + wr * 64 + m * 16 + lhi * 4 + i;
      int bb = p / 50;
      int gg = idx[p];
      const float* Har = Ha + (size_t)bb * 1024;
      const float* Hbr = Hb + (size_t)gg * 1024;
      float s = 0.f;
#pragma unroll
      for (int n = 0; n < 4; ++n) {
        float h = acc[m][n][i] + Har[coln[n]] + Hbr[coln[n]] + b1v[n];
        h = h > 0.f ? h : 0.01f * h;
        s += h * wov[n];
      }
      s += __shfl_xor(s, 1, 64);
      s += __shfl_xor(s, 2, 64);
      s += __shfl_xor(s, 4, 64);
      s += __shfl_xor(s, 8, 64);
      if (llo == 0) partial[(size_t)p * 16 + chunk] = s;
    }
}

__global__ void k_final(const float* __restrict__ partial, const float* __restrict__ rough,
                        const float* __restrict__ bout, float* __restrict__ out) {
  int t = blockIdx.x * 256 + threadIdx.x;
  if (t < 51200) {
    float s = rough[t] + bout[0];
    const float* pp = partial + (size_t)t * 16;
#pragma unroll
    for (int c = 0; c < 16; ++c) s += pp[c];
    out[(size_t)(t / 50) * 51 + 1 + (t % 50)] = s;
  }
  if (t < 1024) out[(size_t)t * 51] = 1e-7f;
}

extern "C" void kernel_launch(void* const* d_in, const int* in_sizes, int n_in,
                              void* d_out, int out_size, void* d_ws, size_t ws_size,
                              hipStream_t stream) {
  (void)in_sizes; (void)n_in; (void)out_size;
  const float* allm  = (const float*)d_in[0];  // [8192][1024]
  const float* am    = (const float*)d_in[1];  // [1024][1024]
  const float* pw    = (const float*)d_in[2];  // [1024][50][64]
  const float* rough = (const float*)d_in[3];  // [1024][50]
  const float* W1    = (const float*)d_in[4];  // [3136][1024]
  const float* b1    = (const float*)d_in[5];  // [1024]
  const float* Wout  = (const float*)d_in[6];  // [1024]
  const float* bout  = (const float*)d_in[7];  // [1]
  const int*   idx   = (const int*)d_in[8];    // [1024][50]
  float* out = (float*)d_out;                  // [1024][51]

  char* w = (char*)d_ws;
  unsigned short* W1T   = (unsigned short*)w; w += (size_t)1024 * 3136 * 2;
  unsigned short* Abm   = (unsigned short*)w; w += (size_t)1024 * 1024 * 2;
  unsigned short* Aball = (unsigned short*)w; w += (size_t)8192 * 1024 * 2;
  unsigned short* P     = (unsigned short*)w; w += (size_t)51200 * 1088 * 2;
  float* Ha             = (float*)w;          w += (size_t)1024 * 1024 * 4;
  float* Hb             = (float*)w;          w += (size_t)8192 * 1024 * 4;
  float* part           = (float*)w;          w += (size_t)51200 * 16 * 4;
  size_t need = (size_t)(w - (char*)d_ws);
  if (ws_size < need) return;

  k_w1t<<<dim3(49, 16), 256, 0, stream>>>(W1, W1T);
  k_cvt<<<dim3(1024), 256, 0, stream>>>(am, Abm, 1024 * 1024 / 4);
  k_cvt<<<dim3(8192), 256, 0, stream>>>(allm, Aball, 8192 * 1024 / 4);
  k_pairs<<<dim3(51200), 256, 0, stream>>>(Abm, Aball, pw, idx, P);
  k_gemm0<<<dim3(8, 8), 256, 0, stream>>>(Abm, 1024, 1024, W1T, 0, Ha);
  k_gemm0<<<dim3(64, 8), 256, 0, stream>>>(Aball, 1024, 1024, W1T, 1024, Hb);
  k_main<<<dim3(3200), 256, 0, stream>>>(P, W1T, part, Ha, Hb, b1, Wout, idx);
  k_final<<<dim3(200), 256, 0, stream>>>(part, rough, bout, out);
}